// Round 2
// baseline (12.944 us; speedup 1.0000x reference)
//
#include <hip/hip_runtime.h>

#define NS 32
#define NH 32

// One thread per point. Only the <=5 segments whose cosine window covers t
// are evaluated. Weights staged in LDS transposed [h][s] so per-lane segment
// gathers are bank-conflict-free (bank index = s).
__global__ __launch_bounds__(256) void springnn_kernel(
    const float* __restrict__ t_in,
    const float* __restrict__ W1,   // [S][1][H]
    const float* __restrict__ b1,   // [S][H]
    const float* __restrict__ W2,   // [S][H][1]
    const float* __restrict__ b2,   // [S][1]
    float* __restrict__ out,
    int N)
{
    __shared__ float2 w1b1[NH][NS];  // [h][s] = (W1[s][0][h], b1[s][h])
    __shared__ float  w2m2[NH][NS];  // [h][s] = -2 * W2[s][h][0]
    __shared__ float  b2eff[NS];     // b2[s] + sum_h W2[s][h]  (tanh folding)

    const int tid = threadIdx.x;

    // ---- stage weights into LDS (transposed) ----
    for (int idx = tid; idx < NS * NH; idx += 256) {
        const int s = idx >> 5;
        const int h = idx & 31;
        w1b1[h][s] = make_float2(W1[s * NH + h], b1[s * NH + h]);
        w2m2[h][s] = -2.0f * W2[s * NH + h];
    }
    if (tid < NS) {
        float acc = b2[tid];
        #pragma unroll
        for (int h = 0; h < NH; ++h) acc += W2[tid * NH + h];
        b2eff[tid] = acc;
    }
    __syncthreads();

    const int n = blockIdx.x * 256 + tid;
    if (n >= N) return;
    const float t = t_in[n];

    // Segments with nonzero window: integers s in [t-2, t+2] (<=5 of them).
    float outv = 0.0f;
    const int s0 = (int)ceilf(t - 2.0f);

    #pragma unroll
    for (int k = 0; k < 5; ++k) {
        const int s = s0 + k;
        const float d = t - (float)s;           // d <= 2 by construction
        if (s >= 0 && s < NS && d >= -2.0f) {
            // window = (1+cos(pi*d/2))/2 = cos^2(pi*d/4); v_cos takes revolutions
            const float c = __builtin_amdgcn_cosf(d * 0.125f);
            const float w = c * c;

            // o = b2 + sum_h tanh(t*w1+b1)*w2
            //   = (b2 + sum_h w2) + sum_h (-2*w2) * rcp(exp(2x)+1)
            float o = b2eff[s];
            #pragma unroll
            for (int h = 0; h < NH; ++h) {
                const float2 wb = w1b1[h][s];
                const float x = fmaf(t, wb.x, wb.y);
                // e^(2x) = 2^(x * 2*log2(e))
                const float e = __builtin_amdgcn_exp2f(x * 2.8853900817779268f);
                const float r = __builtin_amdgcn_rcpf(e + 1.0f);
                o = fmaf(w2m2[h][s], r, o);
            }
            outv = fmaf(w, o, outv);
        }
    }
    out[n] = outv;
}

extern "C" void kernel_launch(void* const* d_in, const int* in_sizes, int n_in,
                              void* d_out, int out_size, void* d_ws, size_t ws_size,
                              hipStream_t stream) {
    const float* t  = (const float*)d_in[0];
    const float* W1 = (const float*)d_in[1];
    const float* b1 = (const float*)d_in[2];
    const float* W2 = (const float*)d_in[3];
    const float* b2 = (const float*)d_in[4];
    // d_in[5]/d_in[6] = xmin/xmax: implied by centers=arange(S), WIDTH=4 (compile-time)
    float* outp = (float*)d_out;
    const int N = in_sizes[0];

    const int block = 256;
    const int grid = (N + block - 1) / block;
    springnn_kernel<<<grid, block, 0, stream>>>(t, W1, b1, W2, b2, outp, N);
}